// Round 6
// baseline (94.920 us; speedup 1.0000x reference)
//
#include <hip/hip_runtime.h>
#include <math.h>

// ---------------------------------------------------------------------------
// FullyQuantumRNN, round 6: algebraic decoupling.
// q_j(x,h) is EXACTLY multilinear in per-wire (1, cos th, sin th) bases
// (pair products of half-angle amplitudes: c^2,cs,s^2 in span{1,cos,sin}).
// => q_j = sum_{p,q} C_j[p,q](x) m_p(h0) m_q(h1),  m=(1,cos,sin).
// S1: evaluate the R5-verified circuit at 243 exact angle combos {0,+-2pi/3}.
// S2: per-wire Vandermonde inversion -> A[18][27] (x-basis coefficients).
// main: phase1 = per-(t,b) C = A*Xb(x) contraction (lane=step, 100% lane
// efficiency, A via uniform scalar loads); phase2 = recurrence with lane=coef,
// 18-term dot + single-DPP butterfly; readout = R1/R5-verified epilogue.
// ---------------------------------------------------------------------------

typedef __attribute__((ext_vector_type(2))) float f2;

// ---- compile-time permutation algebra (R1..R5-verified) ----
constexpr int cnot_ct(int idx, int c, int t) {
    return (idx & (1 << (4 - c))) ? (idx ^ (1 << (4 - t))) : idx;
}
constexpr int Pfwd_ct(int x, int r) {
    for (int w = 4; w >= 0; --w) x = cnot_ct(x, w, (w + r) % 5);
    return x;
}
constexpr int Pinv_ct(int x, int r) {
    for (int w = 0; w <= 4; ++w) x = cnot_ct(x, w, (w + r) % 5);
    return x;
}
static_assert(Pinv_ct(Pfwd_ct(13, 1), 1) == 13, "inv1");
static_assert(Pinv_ct(Pfwd_ct(22, 2), 2) == 22, "inv2");

constexpr int GMASK[10] = {16, 8, 4, 2, 1,
                           Pfwd_ct(16,1), Pfwd_ct(8,1), Pfwd_ct(4,1), Pfwd_ct(2,1), Pfwd_ct(1,1)};
constexpr int fmask_l1(int pb) {
    int f = 0;
    for (int b = 0; b < 5; ++b) if ((Pinv_ct(1 << b, 1) >> pb) & 1) f |= 1 << b;
    return f;
}
constexpr int FMASK[10] = {16, 8, 4, 2, 1,
                           fmask_l1(4), fmask_l1(3), fmask_l1(2), fmask_l1(1), fmask_l1(0)};
constexpr int cinv_ct(int x) { return Pinv_ct(Pinv_ct(x, 1), 2); }
constexpr int fmask_fin(int pb) {
    int f = 0;
    for (int b = 0; b < 5; ++b) if ((cinv_ct(1 << b) >> pb) & 1) f |= 1 << b;
    return f;
}
constexpr int SF3 = fmask_fin(1);
constexpr int SF4 = fmask_fin(0);
constexpr int FMf(int b) { return Pfwd_ct(Pfwd_ct(1 << b, 2), 1); }

constexpr unsigned span3_ct(int a, int b, int c) {
    unsigned m = 0;
    for (int i = 0; i < 8; ++i) {
        int v = ((i & 1) ? a : 0) ^ ((i & 2) ? b : 0) ^ ((i & 4) ? c : 0);
        m |= 1u << v;
    }
    return m;
}
constexpr unsigned PSPAN = span3_ct(FMf(4), FMf(3), FMf(2));
static_assert(PSPAN == span3_ct(16, 1, 14), "p-stage basis {16,1,14} spans PSPAN");
constexpr bool in_pspan(int v) { return (PSPAN >> (v & 31)) & 1; }
constexpr bool pspan_ok() {
    for (int v = 0; v < 32; ++v) if ((PSPAN >> v) & 1) {
        if (__builtin_popcount(v & SF3) & 1) return false;
        if (__builtin_popcount(v & SF4) & 1) return false;
    }
    return true;
}
static_assert(pspan_ok(), "sign functionals vanish on PSPAN");
static_assert((SF3 & 16) == 0 && (SF4 & 16) == 0, "signs lane-only");

constexpr int QM1 = 12;
constexpr int QM0 = 8;
static_assert((QM1 & 16) == 0 && (QM0 & 16) == 0, "q reps lane-only");
static_assert(in_pspan(QM1 ^ FMf(1)), "QM1 ~ FMf(1) mod PSPAN");
static_assert(in_pspan(QM0 ^ FMf(0)), "QM0 ~ FMf(0) mod PSPAN");
static_assert(!in_pspan(QM1) && !in_pspan(QM0) && !in_pspan(QM1 ^ QM0),
              "q reps independent mod duplication subgroup");

// recurrence-side butterfly masks {1,2,7} must span the 3-bit halves
static_assert(span3_ct(1, 2, 7) == 0xFFu, "butterfly {1,2,7} spans lanes 0..7");

// ---- lane relabel A (R5): A(1)=15, A(2)=7, A(4)=2, A(8)=1 ----
constexpr int A4(int l) {
    return ((l & 1) ? 15 : 0) ^ ((l & 2) ? 7 : 0) ^ ((l & 4) ? 2 : 0) ^ ((l & 8) ? 1 : 0);
}
constexpr int Ainv4(int p) {
    for (int l = 0; l < 16; ++l) if (A4(l) == p) return l;
    return -1;
}
constexpr bool a_bij() {
    for (int p = 0; p < 16; ++p) { int l = Ainv4(p); if (l < 0 || A4(l) != p) return false; }
    for (int p = 0; p < 16; ++p) {
        int lin = ((p&1)?Ainv4(1):0) ^ ((p&2)?Ainv4(2):0) ^ ((p&4)?Ainv4(4):0) ^ ((p&8)?Ainv4(8):0);
        if (lin != Ainv4(p)) return false;
    }
    return true;
}
static_assert(a_bij(), "A bijective, inverse linear");

__device__ __forceinline__ int ainv_rt(int p) {
    return ((p & 1) ? Ainv4(1) : 0) ^ ((p & 2) ? Ainv4(2) : 0) ^
           ((p & 4) ? Ainv4(4) : 0) ^ ((p & 8) ? Ainv4(8) : 0);
}
__device__ __forceinline__ int pinv_rt(int x, int r) {
    #pragma unroll
    for (int w = 0; w < 5; ++w) {
        int cbit = 1 << (4 - w), tbit = 1 << (4 - ((w + r) % 5));
        if (x & cbit) x ^= tbit;
    }
    return x;
}

// ---- cross-lane xor move via DPP ----
template<int CTRL> __device__ __forceinline__ float dppf(float x) {
    return __int_as_float(__builtin_amdgcn_mov_dpp(__float_as_int(x), CTRL, 0xF, 0xF, true));
}
template<int PL> __device__ __forceinline__ float mvf(float x) {
    if constexpr (PL == 0)  return x;
    else if constexpr (PL == 1)  return dppf<0xB1>(x);    // quad_perm xor1
    else if constexpr (PL == 2)  return dppf<0x4E>(x);    // quad_perm xor2
    else if constexpr (PL == 3)  return dppf<0x1B>(x);    // quad_perm xor3
    else if constexpr (PL == 7)  return dppf<0x141>(x);   // row_half_mirror = xor7
    else if constexpr (PL == 8)  return dppf<0x128>(x);   // row_ror:8 = xor8
    else if constexpr (PL == 15) return dppf<0x140>(x);   // row_mirror = xor15
    else if constexpr (PL & 8)   return mvf<PL ^ 15>(dppf<0x140>(x));
    else                         return mvf<PL ^ 7>(dppf<0x141>(x));
}

// ---- one Ry gate (R5 verbatim) ----
template<int g>
__device__ __forceinline__ void ry_gate(f2& VR, f2& VI,
                                        const f2 (&C2)[10], const f2 (&S2)[10]) {
    constexpr int m  = GMASK[g];
    constexpr int rm = (m >> 4) & 1;
    constexpr int pl = A4(m & 15);
    f2 PR, PI;
    if constexpr (rm == 0) {
        PR.x = mvf<pl>(VR.x); PR.y = mvf<pl>(VR.y);
        PI.x = mvf<pl>(VI.x); PI.y = mvf<pl>(VI.y);
    } else {
        PR.x = mvf<pl>(VR.y); PR.y = mvf<pl>(VR.x);
        PI.x = mvf<pl>(VI.y); PI.y = mvf<pl>(VI.x);
    }
    VR = C2[g] * VR + S2[g] * PR;
    VI = C2[g] * VI + S2[g] * PI;
}

// ===========================================================================
// S1: evaluate circuit q_j at 243 exact angle combos {0, +2pi/3, -2pi/3}
// (R5-verified step body; half-angle trig of the combo angles is exact)
// ===========================================================================
__global__ __launch_bounds__(256) void qrnn_eval(
    const float* __restrict__ w_rec, float* __restrict__ Q) {
    const int tid = blockIdx.x * blockDim.x + threadIdx.x;
    const int combo = tid >> 4;
    const int lam = tid & 15;
    if (combo >= 243) return;
    const int l = ainv_rt(lam);

    // prologue (R5 verbatim, libm precision)
    f2 C2[10], S2[10];
    #pragma unroll
    for (int g = 0; g < 10; ++g) {
        const float the = w_rec[(g / 5) * 15 + (g % 5) * 3 + 1];
        const float c = cosf(0.5f * the), s = sinf(0.5f * the);
        const bool bl = __popc(l & (FMASK[g] & 15)) & 1;
        const bool fb = (FMASK[g] >> 4) & 1;
        const float sg = bl ? s : -s;
        C2[g].x = c;  C2[g].y = c;
        S2[g].x = sg; S2[g].y = fb ? -sg : sg;
    }
    f2 P0r2, P0i2, E1r2, E1i2;
    #pragma unroll
    for (int r = 0; r < 2; ++r) {
        const int s_idx = (r << 4) | l;
        const int j     = pinv_rt(s_idx, 1);
        float a0 = 0.f, e1 = 0.f;
        #pragma unroll
        for (int w = 0; w < 5; ++w) {
            const float sg0 = ((s_idx >> (4 - w)) & 1) ? 0.5f : -0.5f;
            const float sg1 = ((j     >> (4 - w)) & 1) ? 0.5f : -0.5f;
            a0 += sg0 * w_rec[w * 3 + 0];
            e1 += sg0 * w_rec[w * 3 + 2];
            e1 += sg1 * w_rec[15 + w * 3 + 0];
        }
        if (r == 0) { P0r2.x = cosf(a0); P0i2.x = sinf(a0);
                      E1r2.x = cosf(e1); E1i2.x = sinf(e1); }
        else        { P0r2.y = cosf(a0); P0i2.y = sinf(a0);
                      E1r2.y = cosf(e1); E1i2.y = sinf(e1); }
    }
    const float s3f = (__popc(l & SF3) & 1) ? -1.f : 1.f;
    const float s4f = (__popc(l & SF4) & 1) ? -1.f : 1.f;

    // combo digits -> exact half-angle trig (angles {0, +2pi/3, -2pi/3})
    const int d0 = combo / 81, d1 = (combo / 27) % 3, d2 = (combo / 9) % 3,
              d3 = (combo / 3) % 3, d4 = combo % 3;
    const float CH[3] = {1.f, 0.5f, 0.5f};
    const float SH[3] = {0.f, 0.86602540378443865f, -0.86602540378443865f};
    const float c0  = CH[d0], s0 = SH[d0];
    const float f1  = (l & 8) ? SH[d1] : CH[d1];
    const float f2v = (l & 4) ? SH[d2] : CH[d2];
    const float f3  = (l & 2) ? SH[d3] : CH[d3];
    const float f4  = (l & 1) ? SH[d4] : CH[d4];

    const float Xl = (f1 * f2v) * (f3 * f4);
    f2 bp; bp.x = c0 * Xl; bp.y = s0 * Xl;
    f2 VR = bp * P0r2;
    f2 VI = bp * P0i2;

    ry_gate<0>(VR, VI, C2, S2); ry_gate<1>(VR, VI, C2, S2);
    ry_gate<2>(VR, VI, C2, S2); ry_gate<3>(VR, VI, C2, S2);
    ry_gate<4>(VR, VI, C2, S2);
    {
        const f2 nr = VR * E1r2 - VI * E1i2;
        const f2 ni = VR * E1i2 + VI * E1r2;
        VR = nr; VI = ni;
    }
    ry_gate<5>(VR, VI, C2, S2); ry_gate<6>(VR, VI, C2, S2);
    ry_gate<7>(VR, VI, C2, S2); ry_gate<8>(VR, VI, C2, S2);
    ry_gate<9>(VR, VI, C2, S2);

    const f2 P = VR * VR + VI * VI;
    float tq = P.x + P.y;
    tq += mvf<A4(1)>(tq);
    tq += mvf<A4(14)>(tq);
    float q0 = s3f * tq, q1 = s4f * tq;
    q0 += mvf<A4(QM1)>(q0); q1 += mvf<A4(QM1)>(q1);
    q0 += mvf<A4(QM0)>(q0); q1 += mvf<A4(QM0)>(q1);

    if (lam == 0) { Q[combo * 2 + 0] = q0; Q[combo * 2 + 1] = q1; }
}

// ===========================================================================
// S2: per-wire Vandermonde inversion: A[row=j*9+p*3+q][col=a0*9+a1*3+a2]
// V rows m(theta) for theta in {0, 2pi/3, -2pi/3}; W = V^-1 (verified W*V=I)
// ===========================================================================
__global__ __launch_bounds__(256) void qrnn_contract(
    const float* __restrict__ Q, float* __restrict__ A) {
    const int o = blockIdx.x * blockDim.x + threadIdx.x;
    if (o >= 486) return;
    const int row = o / 27, col = o % 27;
    const int j = row / 9, pq = row % 9, p = pq / 3, q = pq % 3;
    const int a0 = col / 9, a1 = (col / 3) % 3, a2 = col % 3;
    const float W[3][3] = {{1.f/3.f, 1.f/3.f, 1.f/3.f},
                           {2.f/3.f, -1.f/3.f, -1.f/3.f},
                           {0.f, 0.57735026918962576f, -0.57735026918962576f}};
    float acc = 0.f;
    for (int d0 = 0; d0 < 3; ++d0)
    for (int d1 = 0; d1 < 3; ++d1)
    for (int d2 = 0; d2 < 3; ++d2) {
        const float w012 = W[a0][d0] * W[a1][d1] * W[a2][d2];
        for (int d3 = 0; d3 < 3; ++d3)
        for (int d4 = 0; d4 < 3; ++d4) {
            const int c = (((d0 * 3 + d1) * 3 + d2) * 3 + d3) * 3 + d4;
            acc = fmaf(w012 * W[p][d3] * W[q][d4], Q[c * 2 + j], acc);
        }
    }
    A[row * 27 + col] = acc;
}

// ===========================================================================
// main: phase1 C=A*Xb per (t,b) (lane=step), phase2 recurrence (lane=coef)
// T hardcoded 32 (bench-fixed): 16 lanes x 2 steps each.
// ===========================================================================
__global__ __launch_bounds__(256, 2) void qrnn_main(
    const float* __restrict__ x_seq, const float* __restrict__ w_out,
    const float* __restrict__ A, float* __restrict__ out, int B) {

    __shared__ float4 xs4[16 * 32];      // staged x, [local-batch][step]
    __shared__ float  Cm[16][19][33];    // [local-batch][row 0..17 + zero-row][t], +1 pad

    const int tloc = threadIdx.x;
    const int g = tloc >> 4;             // local batch 0..15
    const int k = tloc & 15;             // lane-in-group
    const int b0 = blockIdx.x * 16;
    const int b = b0 + g;

    // ---- stage x (coalesced, R5 pattern) ----
    #pragma unroll
    for (int qq = 0; qq < 2; ++qq) {
        const int p = tloc + qq * 256;
        const int ts = p >> 4, lbs = p & 15;
        const int gidx = (ts * B + (b0 + lbs)) * 3;
        float4 v;
        v.x = x_seq[gidx]; v.y = x_seq[gidx + 1]; v.z = x_seq[gidx + 2]; v.w = 0.f;
        xs4[lbs * 32 + ts] = v;
    }
    __syncthreads();

    constexpr float Kf = 0.15915494309189535f;   // 1/(2*pi): full-angle rad->rev

    // ---- phase 1: lane (g,k) computes C rows for steps k and k+16 ----
    #pragma unroll 1
    for (int tt = 0; tt < 2; ++tt) {
        const int t = k + 16 * tt;
        const float4 xv = xs4[g * 32 + t];
        const float cx0 = __builtin_amdgcn_cosf(xv.x * Kf);
        const float sx0 = __builtin_amdgcn_cosf(fmaf(xv.x, Kf, -0.25f));
        const float cx1 = __builtin_amdgcn_cosf(xv.y * Kf);
        const float sx1 = __builtin_amdgcn_cosf(fmaf(xv.y, Kf, -0.25f));
        const float cx2 = __builtin_amdgcn_cosf(xv.z * Kf);
        const float sx2 = __builtin_amdgcn_cosf(fmaf(xv.z, Kf, -0.25f));
        float Xb[27];
        Xb[0] = 1.f;  Xb[1] = cx2;       Xb[2] = sx2;
        Xb[3] = cx1;  Xb[4] = cx1 * cx2; Xb[5] = cx1 * sx2;
        Xb[6] = sx1;  Xb[7] = sx1 * cx2; Xb[8] = sx1 * sx2;
        #pragma unroll
        for (int i = 0; i < 9; ++i) { Xb[9 + i] = cx0 * Xb[i]; Xb[18 + i] = sx0 * Xb[i]; }
        #pragma unroll 1
        for (int row = 0; row < 18; ++row) {
            const float* Ar = A + row * 27;       // uniform -> scalar loads
            float p4[4] = {0.f, 0.f, 0.f, 0.f};
            #pragma unroll
            for (int i = 0; i < 27; ++i) p4[i & 3] = fmaf(Ar[i], Xb[i], p4[i & 3]);
            Cm[g][row][t] = (p4[0] + p4[1]) + (p4[2] + p4[3]);
        }
        Cm[g][18][t] = 0.f;                       // zero row for rowB padding
    }
    // C written/read within the same wave (group = 16 lanes) -> no barrier

    // ---- phase 2: recurrence; lane k = coefficient slot ----
    // k 0..7: j0 terms (p,q)=idx 1..8; k 8..15: j1 terms; (0,0) consts via rowB
    const int jj = k >> 3;
    const int term = (k & 7) + 1;
    const int rowA = jj * 9 + term;
    const int rowB = (k == 0) ? 0 : ((k == 8) ? 9 : 18);
    const int p = term / 3, q = term % 3;
    const float* CA_ptr = &Cm[g][rowA][0];
    const float* CB_ptr = &Cm[g][rowB][0];

    float h0 = 0.f, h1 = 0.f;
    float CA = CA_ptr[0], CB = CB_ptr[0];
    #pragma unroll 1
    for (int t = 0; t < 32; ++t) {
        const int tn = (t < 31) ? t + 1 : 31;
        const float CAn = CA_ptr[tn], CBn = CB_ptr[tn];   // prefetch next step
        const float ch0 = __builtin_amdgcn_cosf(h0 * Kf);
        const float sh0 = __builtin_amdgcn_cosf(fmaf(h0, Kf, -0.25f));
        const float ch1 = __builtin_amdgcn_cosf(h1 * Kf);
        const float sh1 = __builtin_amdgcn_cosf(fmaf(h1, Kf, -0.25f));
        const float u = (p == 1) ? ch0 : ((p == 2) ? sh0 : 1.f);
        const float v = (q == 1) ? ch1 : ((q == 2) ? sh1 : 1.f);
        float val = fmaf(CA, u * v, CB);
        val += mvf<1>(val);                // butterfly {1,2,7}: sums 8-halves
        val += mvf<2>(val);
        val += mvf<7>(val);
        const float other = mvf<8>(val);   // xor8 via row_ror:8
        h0 = (k & 8) ? other : val;        // q_j0 in all lanes
        h1 = (k & 8) ? val : other;        // q_j1 in all lanes
        CA = CAn; CB = CBn;
    }

    // ---- readout: 2-qubit circuit (R1/R5-verified), libm trig ----
    const float sh0 = sinf(0.5f * h0), ch0 = cosf(0.5f * h0);
    const float sh1 = sinf(0.5f * h1), ch1 = cosf(0.5f * h1);
    float vr0 = ch0 * ch1, vr1 = ch0 * sh1, vr2 = sh0 * ch1, vr3 = sh0 * sh1;
    float vi0 = 0.f, vi1 = 0.f, vi2 = 0.f, vi3 = 0.f;

    #pragma unroll
    for (int li = 0; li < 2; ++li) {
        #pragma unroll
        for (int w = 0; w < 2; ++w) {
            const float phi = w_out[li * 6 + w * 3 + 0];
            const float the = w_out[li * 6 + w * 3 + 1];
            const float ome = w_out[li * 6 + w * 3 + 2];
            const float cs = cosf(0.5f * the), ss = sinf(0.5f * the);
            const float cp = cosf(0.5f * (phi + ome)), sp = sinf(0.5f * (phi + ome));
            const float cm = cosf(0.5f * (phi - ome)), sm = sinf(0.5f * (phi - ome));
            const float are = cp * cs, aim = -sp * cs;
            const float bre = cm * ss, bim = sm * ss;
            #define AP2(r0, i0, r1, i1) do {                                  \
                float n0r = are*(r0) - aim*(i0) - bre*(r1) + bim*(i1);        \
                float n0i = are*(i0) + aim*(r0) - bre*(i1) - bim*(r1);        \
                float n1r = bre*(r0) + bim*(i0) + are*(r1) + aim*(i1);        \
                float n1i = bre*(i0) - bim*(r0) + are*(i1) - aim*(r1);        \
                r0 = n0r; i0 = n0i; r1 = n1r; i1 = n1i; } while (0)
            if (w == 0) { AP2(vr0, vi0, vr2, vi2); AP2(vr1, vi1, vr3, vi3); }
            else        { AP2(vr0, vi0, vr1, vi1); AP2(vr2, vi2, vr3, vi3); }
            #undef AP2
        }
        float tr1 = vr2, ti1 = vi2, tr2 = vr3, ti2 = vi3, tr3 = vr1, ti3 = vi1;
        vr1 = tr1; vi1 = ti1; vr2 = tr2; vi2 = ti2; vr3 = tr3; vi3 = ti3;
    }

    const float outv = (vr0 * vr0 + vi0 * vi0 + vr1 * vr1 + vi1 * vi1) -
                       (vr2 * vr2 + vi2 * vi2 + vr3 * vr3 + vi3 * vi3);
    if (k == 0) out[b] = outv;
}

extern "C" void kernel_launch(void* const* d_in, const int* in_sizes, int n_in,
                              void* d_out, int out_size, void* d_ws, size_t ws_size,
                              hipStream_t stream) {
    const float* x_seq = (const float*)d_in[0];
    const float* w_rec = (const float*)d_in[1];
    const float* w_out = (const float*)d_in[2];
    float* out = (float*)d_out;
    float* Q = (float*)d_ws;            // 486 floats
    float* A = (float*)d_ws + 512;      // 486 floats

    const int B = out_size;             // 8192 (T fixed at 32 by the bench)

    hipLaunchKernelGGL(qrnn_eval,     dim3(16), dim3(256), 0, stream, w_rec, Q);
    hipLaunchKernelGGL(qrnn_contract, dim3(2),  dim3(256), 0, stream, Q, A);
    hipLaunchKernelGGL(qrnn_main,     dim3((B * 16) / 256), dim3(256), 0, stream,
                       x_seq, w_out, A, out, B);
}

// Round 8
// 88.672 us; speedup vs baseline: 1.0705x; 1.0705x over previous
//
#include <hip/hip_runtime.h>
#include <math.h>

// ---------------------------------------------------------------------------
// FullyQuantumRNN, round 8: ONE standard kernel, self-sufficient blocks.
// R6-validated pipeline (absmax 1.8e-7): q_j(x,h) is exactly multilinear in
// per-wire (1,cos,sin) bases -> q_j = sum_pq C_j[p,q](x) m_p(h0) m_q(h1).
// Each block redundantly: (a) evaluates the circuit at 243 exact angle combos
// {0,+-2pi/3} (16 combos per 16-lane group, per-lane prologue hoisted),
// (b) separable 5-stage W=V^-1 transform in LDS -> A[18][27],
// (c) phase1: per-(t,b) C = A.Xb(x) with uniform ds_read_b128 A-rows,
// (d) phase2: 18-term recurrence, single-DPP butterfly; readout epilogue.
// No cooperative launch (R7: silently failed), no multi-kernel (R6: ~10us/node
// overhead dominated). Setup is ~2k instr/wave -> redundancy is cheap.
// ---------------------------------------------------------------------------

typedef __attribute__((ext_vector_type(2))) float f2;

// ---- compile-time permutation algebra (R1..R6-verified) ----
constexpr int cnot_ct(int idx, int c, int t) {
    return (idx & (1 << (4 - c))) ? (idx ^ (1 << (4 - t))) : idx;
}
constexpr int Pfwd_ct(int x, int r) {
    for (int w = 4; w >= 0; --w) x = cnot_ct(x, w, (w + r) % 5);
    return x;
}
constexpr int Pinv_ct(int x, int r) {
    for (int w = 0; w <= 4; ++w) x = cnot_ct(x, w, (w + r) % 5);
    return x;
}
static_assert(Pinv_ct(Pfwd_ct(13, 1), 1) == 13, "inv1");
static_assert(Pinv_ct(Pfwd_ct(22, 2), 2) == 22, "inv2");

constexpr int GMASK[10] = {16, 8, 4, 2, 1,
                           Pfwd_ct(16,1), Pfwd_ct(8,1), Pfwd_ct(4,1), Pfwd_ct(2,1), Pfwd_ct(1,1)};
constexpr int fmask_l1(int pb) {
    int f = 0;
    for (int b = 0; b < 5; ++b) if ((Pinv_ct(1 << b, 1) >> pb) & 1) f |= 1 << b;
    return f;
}
constexpr int FMASK[10] = {16, 8, 4, 2, 1,
                           fmask_l1(4), fmask_l1(3), fmask_l1(2), fmask_l1(1), fmask_l1(0)};
constexpr int cinv_ct(int x) { return Pinv_ct(Pinv_ct(x, 1), 2); }
constexpr int fmask_fin(int pb) {
    int f = 0;
    for (int b = 0; b < 5; ++b) if ((cinv_ct(1 << b) >> pb) & 1) f |= 1 << b;
    return f;
}
constexpr int SF3 = fmask_fin(1);
constexpr int SF4 = fmask_fin(0);
constexpr int FMf(int b) { return Pfwd_ct(Pfwd_ct(1 << b, 2), 1); }

constexpr unsigned span3_ct(int a, int b, int c) {
    unsigned m = 0;
    for (int i = 0; i < 8; ++i) {
        int v = ((i & 1) ? a : 0) ^ ((i & 2) ? b : 0) ^ ((i & 4) ? c : 0);
        m |= 1u << v;
    }
    return m;
}
constexpr unsigned PSPAN = span3_ct(FMf(4), FMf(3), FMf(2));
static_assert(PSPAN == span3_ct(16, 1, 14), "p-stage basis {16,1,14} spans PSPAN");
constexpr bool in_pspan(int v) { return (PSPAN >> (v & 31)) & 1; }
constexpr bool pspan_ok() {
    for (int v = 0; v < 32; ++v) if ((PSPAN >> v) & 1) {
        if (__builtin_popcount(v & SF3) & 1) return false;
        if (__builtin_popcount(v & SF4) & 1) return false;
    }
    return true;
}
static_assert(pspan_ok(), "sign functionals vanish on PSPAN");
static_assert((SF3 & 16) == 0 && (SF4 & 16) == 0, "signs lane-only");

constexpr int QM1 = 12;
constexpr int QM0 = 8;
static_assert((QM1 & 16) == 0 && (QM0 & 16) == 0, "q reps lane-only");
static_assert(in_pspan(QM1 ^ FMf(1)), "QM1 ~ FMf(1) mod PSPAN");
static_assert(in_pspan(QM0 ^ FMf(0)), "QM0 ~ FMf(0) mod PSPAN");
static_assert(!in_pspan(QM1) && !in_pspan(QM0) && !in_pspan(QM1 ^ QM0),
              "q reps independent mod duplication subgroup");
static_assert(span3_ct(1, 2, 7) == 0xFFu, "butterfly {1,2,7} spans lanes 0..7");

// ---- lane relabel A (R5/R6): A(1)=15, A(2)=7, A(4)=2, A(8)=1 ----
constexpr int A4(int l) {
    return ((l & 1) ? 15 : 0) ^ ((l & 2) ? 7 : 0) ^ ((l & 4) ? 2 : 0) ^ ((l & 8) ? 1 : 0);
}
constexpr int Ainv4(int p) {
    for (int l = 0; l < 16; ++l) if (A4(l) == p) return l;
    return -1;
}
constexpr bool a_bij() {
    for (int p = 0; p < 16; ++p) { int l = Ainv4(p); if (l < 0 || A4(l) != p) return false; }
    for (int p = 0; p < 16; ++p) {
        int lin = ((p&1)?Ainv4(1):0) ^ ((p&2)?Ainv4(2):0) ^ ((p&4)?Ainv4(4):0) ^ ((p&8)?Ainv4(8):0);
        if (lin != Ainv4(p)) return false;
    }
    return true;
}
static_assert(a_bij(), "A bijective, inverse linear");

__device__ __forceinline__ int ainv_rt(int p) {
    return ((p & 1) ? Ainv4(1) : 0) ^ ((p & 2) ? Ainv4(2) : 0) ^
           ((p & 4) ? Ainv4(4) : 0) ^ ((p & 8) ? Ainv4(8) : 0);
}
__device__ __forceinline__ int pinv_rt(int x, int r) {
    #pragma unroll
    for (int w = 0; w < 5; ++w) {
        int cbit = 1 << (4 - w), tbit = 1 << (4 - ((w + r) % 5));
        if (x & cbit) x ^= tbit;
    }
    return x;
}

// ---- cross-lane xor move via DPP (all patterns stay within 16-lane rows) ----
template<int CTRL> __device__ __forceinline__ float dppf(float x) {
    return __int_as_float(__builtin_amdgcn_mov_dpp(__float_as_int(x), CTRL, 0xF, 0xF, true));
}
template<int PL> __device__ __forceinline__ float mvf(float x) {
    if constexpr (PL == 0)  return x;
    else if constexpr (PL == 1)  return dppf<0xB1>(x);    // quad_perm xor1
    else if constexpr (PL == 2)  return dppf<0x4E>(x);    // quad_perm xor2
    else if constexpr (PL == 3)  return dppf<0x1B>(x);    // quad_perm xor3
    else if constexpr (PL == 7)  return dppf<0x141>(x);   // row_half_mirror = xor7
    else if constexpr (PL == 8)  return dppf<0x128>(x);   // row_ror:8 = xor8
    else if constexpr (PL == 15) return dppf<0x140>(x);   // row_mirror = xor15
    else if constexpr (PL & 8)   return mvf<PL ^ 15>(dppf<0x140>(x));
    else                         return mvf<PL ^ 7>(dppf<0x141>(x));
}

// ---- one Ry gate (R5/R6 verbatim) ----
template<int g>
__device__ __forceinline__ void ry_gate(f2& VR, f2& VI,
                                        const f2 (&C2)[10], const f2 (&S2)[10]) {
    constexpr int m  = GMASK[g];
    constexpr int rm = (m >> 4) & 1;
    constexpr int pl = A4(m & 15);
    f2 PR, PI;
    if constexpr (rm == 0) {
        PR.x = mvf<pl>(VR.x); PR.y = mvf<pl>(VR.y);
        PI.x = mvf<pl>(VI.x); PI.y = mvf<pl>(VI.y);
    } else {
        PR.x = mvf<pl>(VR.y); PR.y = mvf<pl>(VR.x);
        PI.x = mvf<pl>(VI.y); PI.y = mvf<pl>(VI.x);
    }
    VR = C2[g] * VR + S2[g] * PR;
    VI = C2[g] * VI + S2[g] * PI;
}

__global__ __launch_bounds__(256, 2) void qrnn_all(
    const float* __restrict__ x_seq, const float* __restrict__ w_rec,
    const float* __restrict__ w_out, float* __restrict__ out, int B) {

    __shared__ __align__(16) float4 xs4[16 * 32];   // [local-batch][step]
    __shared__ float Qa[488], Qb[488];              // eval results / ping-pong
    __shared__ __align__(16) float A2s[18 * 28];    // row-major A, padded to 28
    __shared__ float Cm[16][19][33];                // per-(batch,row,t) coefs

    const int tloc = threadIdx.x;
    const int grp  = tloc >> 4;          // group / local batch 0..15
    const int k    = tloc & 15;          // lane-in-group
    const int b0   = blockIdx.x * 16;
    const int b    = b0 + grp;

    // ---- stage x (coalesced; consumed after later barriers) ----
    #pragma unroll
    for (int qq = 0; qq < 2; ++qq) {
        const int p = tloc + qq * 256;
        const int ts = p >> 4, lbs = p & 15;
        const int gidx = (ts * B + (b0 + lbs)) * 3;
        float4 v;
        v.x = x_seq[gidx]; v.y = x_seq[gidx + 1]; v.z = x_seq[gidx + 2]; v.w = 0.f;
        xs4[lbs * 32 + ts] = v;
    }

    // ======== eval (per-block, redundant): 16 combos per 16-lane group ========
    {
        const int l = ainv_rt(k);
        // per-lane prologue (libm precision), hoisted over the combo loop
        f2 C2[10], S2[10];
        #pragma unroll
        for (int gg = 0; gg < 10; ++gg) {
            const float the = w_rec[(gg / 5) * 15 + (gg % 5) * 3 + 1];
            const float c = cosf(0.5f * the), s = sinf(0.5f * the);
            const bool bl = __popc(l & (FMASK[gg] & 15)) & 1;
            const bool fb = (FMASK[gg] >> 4) & 1;
            const float sg = bl ? s : -s;
            C2[gg].x = c;  C2[gg].y = c;
            S2[gg].x = sg; S2[gg].y = fb ? -sg : sg;
        }
        f2 P0r2, P0i2, E1r2, E1i2;
        #pragma unroll
        for (int r = 0; r < 2; ++r) {
            const int s_idx = (r << 4) | l;
            const int j     = pinv_rt(s_idx, 1);
            float a0 = 0.f, e1 = 0.f;
            #pragma unroll
            for (int w = 0; w < 5; ++w) {
                const float sg0 = ((s_idx >> (4 - w)) & 1) ? 0.5f : -0.5f;
                const float sg1 = ((j     >> (4 - w)) & 1) ? 0.5f : -0.5f;
                a0 += sg0 * w_rec[w * 3 + 0];
                e1 += sg0 * w_rec[w * 3 + 2];
                e1 += sg1 * w_rec[15 + w * 3 + 0];
            }
            if (r == 0) { P0r2.x = cosf(a0); P0i2.x = sinf(a0);
                          E1r2.x = cosf(e1); E1i2.x = sinf(e1); }
            else        { P0r2.y = cosf(a0); P0i2.y = sinf(a0);
                          E1r2.y = cosf(e1); E1i2.y = sinf(e1); }
        }
        const float s3f = (__popc(l & SF3) & 1) ? -1.f : 1.f;
        const float s4f = (__popc(l & SF4) & 1) ? -1.f : 1.f;
        const float CH[3] = {1.f, 0.5f, 0.5f};
        const float SH[3] = {0.f, 0.86602540378443865f, -0.86602540378443865f};

        #pragma unroll 1
        for (int ci = 0; ci < 16; ++ci) {
            const int combo = grp + (ci << 4);      // grp-strided: balanced
            if (combo < 243) {
                const int d0 = combo / 81, d1 = (combo / 27) % 3, d2 = (combo / 9) % 3,
                          d3 = (combo / 3) % 3, d4 = combo % 3;
                const float c0  = CH[d0], s0 = SH[d0];
                const float f1  = (l & 8) ? SH[d1] : CH[d1];
                const float f2v = (l & 4) ? SH[d2] : CH[d2];
                const float f3  = (l & 2) ? SH[d3] : CH[d3];
                const float f4  = (l & 1) ? SH[d4] : CH[d4];

                const float Xl = (f1 * f2v) * (f3 * f4);
                f2 bp; bp.x = c0 * Xl; bp.y = s0 * Xl;
                f2 VR = bp * P0r2;
                f2 VI = bp * P0i2;

                ry_gate<0>(VR, VI, C2, S2); ry_gate<1>(VR, VI, C2, S2);
                ry_gate<2>(VR, VI, C2, S2); ry_gate<3>(VR, VI, C2, S2);
                ry_gate<4>(VR, VI, C2, S2);
                {
                    const f2 nr = VR * E1r2 - VI * E1i2;
                    const f2 ni = VR * E1i2 + VI * E1r2;
                    VR = nr; VI = ni;
                }
                ry_gate<5>(VR, VI, C2, S2); ry_gate<6>(VR, VI, C2, S2);
                ry_gate<7>(VR, VI, C2, S2); ry_gate<8>(VR, VI, C2, S2);
                ry_gate<9>(VR, VI, C2, S2);

                const f2 P = VR * VR + VI * VI;
                float tq = P.x + P.y;
                tq += mvf<A4(1)>(tq);
                tq += mvf<A4(14)>(tq);
                float q0 = s3f * tq, q1 = s4f * tq;
                q0 += mvf<A4(QM1)>(q0); q1 += mvf<A4(QM1)>(q1);
                q0 += mvf<A4(QM0)>(q0); q1 += mvf<A4(QM0)>(q1);

                if (k == 0) { Qa[combo * 2 + 0] = q0; Qa[combo * 2 + 1] = q1; }
            }
        }
    }
    __syncthreads();

    // ======== separable contract: 5 W-stages (each moves fastest digit to
    // slowest-transformed); final order a0 a1 a2 a3 a4; ends in Qb ========
    {
        const float* ins[5]  = {Qa, Qb, Qa, Qb, Qa};
        float* outs[5]       = {Qb, Qa, Qb, Qa, Qb};
        #pragma unroll
        for (int s = 0; s < 5; ++s) {
            const float* in = ins[s];
            float* ob = outs[s];
            for (int o = tloc; o < 486; o += 256) {
                const int j = o & 1, e = o >> 1;
                const int a = e / 81, r = e % 81;
                const float v0 = in[(r * 3 + 0) * 2 + j];
                const float v1 = in[(r * 3 + 1) * 2 + j];
                const float v2 = in[(r * 3 + 2) * 2 + j];
                float wv;
                if (a == 0)      wv = (v0 + v1 + v2) * (1.f / 3.f);
                else if (a == 1) wv = fmaf(2.f / 3.f, v0, -(1.f / 3.f) * (v1 + v2));
                else             wv = 0.57735026918962576f * (v1 - v2);
                ob[(a * 81 + r) * 2 + j] = wv;
            }
            __syncthreads();
        }
    }
    // transpose: A2s[row=j*9+p*3+q][col=a0*9+a1*3+a2] = G[a0..a2, p=a3, q=a4, j]
    for (int o = tloc; o < 486; o += 256) {
        const int row = o / 27, col = o % 27;
        const int j = row / 9, pq = row % 9;
        A2s[row * 28 + col] = Qb[(col * 9 + pq) * 2 + j];
    }
    if (tloc < 18) A2s[tloc * 28 + 27] = 0.f;
    __syncthreads();

    // ======== phase 1: C[t][row] = A-row . Xb(t); lane (grp,k) -> t=k,k+16 ====
    constexpr float Kf = 0.15915494309189535f;   // 1/(2*pi)
    float Xb0[28], Xb1[28];
    #pragma unroll
    for (int tt = 0; tt < 2; ++tt) {
        float* Xb = tt ? Xb1 : Xb0;
        const float4 xv = xs4[grp * 32 + k + 16 * tt];
        const float cx0 = __builtin_amdgcn_cosf(xv.x * Kf);
        const float sx0 = __builtin_amdgcn_cosf(fmaf(xv.x, Kf, -0.25f));
        const float cx1 = __builtin_amdgcn_cosf(xv.y * Kf);
        const float sx1 = __builtin_amdgcn_cosf(fmaf(xv.y, Kf, -0.25f));
        const float cx2 = __builtin_amdgcn_cosf(xv.z * Kf);
        const float sx2 = __builtin_amdgcn_cosf(fmaf(xv.z, Kf, -0.25f));
        Xb[0] = 1.f;  Xb[1] = cx2;       Xb[2] = sx2;
        Xb[3] = cx1;  Xb[4] = cx1 * cx2; Xb[5] = cx1 * sx2;
        Xb[6] = sx1;  Xb[7] = sx1 * cx2; Xb[8] = sx1 * sx2;
        #pragma unroll
        for (int i = 0; i < 9; ++i) { Xb[9 + i] = cx0 * Xb[i]; Xb[18 + i] = sx0 * Xb[i]; }
        Xb[27] = 0.f;
    }
    {
        const float4* A4p = (const float4*)A2s;
        #pragma unroll 1
        for (int r = 0; r < 18; ++r) {
            float4 av[7];
            #pragma unroll
            for (int i = 0; i < 7; ++i) av[i] = A4p[r * 7 + i];   // uniform b128
            float a00 = 0.f, a01 = 0.f, a10 = 0.f, a11 = 0.f;
            #pragma unroll
            for (int i = 0; i < 7; ++i) {
                a00 = fmaf(av[i].x, Xb0[4*i+0], a00); a00 = fmaf(av[i].y, Xb0[4*i+1], a00);
                a01 = fmaf(av[i].z, Xb0[4*i+2], a01); a01 = fmaf(av[i].w, Xb0[4*i+3], a01);
                a10 = fmaf(av[i].x, Xb1[4*i+0], a10); a10 = fmaf(av[i].y, Xb1[4*i+1], a10);
                a11 = fmaf(av[i].z, Xb1[4*i+2], a11); a11 = fmaf(av[i].w, Xb1[4*i+3], a11);
            }
            Cm[grp][r][k]      = a00 + a01;
            Cm[grp][r][k + 16] = a10 + a11;
        }
        Cm[grp][18][k] = 0.f; Cm[grp][18][k + 16] = 0.f;
    }
    // C written/read within the same wave (16-lane group) -> no barrier (R6-ok)

    // ======== phase 2: recurrence; lane k = coefficient slot (R6 verbatim) ====
    const int jj = k >> 3;
    const int term = (k & 7) + 1;
    const int rowA = jj * 9 + term;
    const int rowB = (k == 0) ? 0 : ((k == 8) ? 9 : 18);
    const int p = term / 3, q = term % 3;
    const float* CA_ptr = &Cm[grp][rowA][0];
    const float* CB_ptr = &Cm[grp][rowB][0];

    float h0 = 0.f, h1 = 0.f;
    float CA = CA_ptr[0], CB = CB_ptr[0];
    #pragma unroll 1
    for (int t = 0; t < 32; ++t) {
        const int tn = (t < 31) ? t + 1 : 31;
        const float CAn = CA_ptr[tn], CBn = CB_ptr[tn];
        const float ch0 = __builtin_amdgcn_cosf(h0 * Kf);
        const float sh0 = __builtin_amdgcn_cosf(fmaf(h0, Kf, -0.25f));
        const float ch1 = __builtin_amdgcn_cosf(h1 * Kf);
        const float sh1 = __builtin_amdgcn_cosf(fmaf(h1, Kf, -0.25f));
        const float u = (p == 1) ? ch0 : ((p == 2) ? sh0 : 1.f);
        const float v = (q == 1) ? ch1 : ((q == 2) ? sh1 : 1.f);
        float val = fmaf(CA, u * v, CB);
        val += mvf<1>(val);
        val += mvf<2>(val);
        val += mvf<7>(val);
        const float other = mvf<8>(val);
        h0 = (k & 8) ? other : val;
        h1 = (k & 8) ? val : other;
        CA = CAn; CB = CBn;
    }

    // ---- readout: 2-qubit circuit (R1/R5/R6-verified), libm trig ----
    const float sh0 = sinf(0.5f * h0), ch0 = cosf(0.5f * h0);
    const float sh1 = sinf(0.5f * h1), ch1 = cosf(0.5f * h1);
    float vr0 = ch0 * ch1, vr1 = ch0 * sh1, vr2 = sh0 * ch1, vr3 = sh0 * sh1;
    float vi0 = 0.f, vi1 = 0.f, vi2 = 0.f, vi3 = 0.f;

    #pragma unroll
    for (int li = 0; li < 2; ++li) {
        #pragma unroll
        for (int w = 0; w < 2; ++w) {
            const float phi = w_out[li * 6 + w * 3 + 0];
            const float the = w_out[li * 6 + w * 3 + 1];
            const float ome = w_out[li * 6 + w * 3 + 2];
            const float cs = cosf(0.5f * the), ss = sinf(0.5f * the);
            const float cp = cosf(0.5f * (phi + ome)), sp = sinf(0.5f * (phi + ome));
            const float cm = cosf(0.5f * (phi - ome)), sm = sinf(0.5f * (phi - ome));
            const float are = cp * cs, aim = -sp * cs;
            const float bre = cm * ss, bim = sm * ss;
            #define AP2(r0, i0, r1, i1) do {                                  \
                float n0r = are*(r0) - aim*(i0) - bre*(r1) + bim*(i1);        \
                float n0i = are*(i0) + aim*(r0) - bre*(i1) - bim*(r1);        \
                float n1r = bre*(r0) + bim*(i0) + are*(r1) + aim*(i1);        \
                float n1i = bre*(i0) - bim*(r0) + are*(i1) - aim*(r1);        \
                r0 = n0r; i0 = n0i; r1 = n1r; i1 = n1i; } while (0)
            if (w == 0) { AP2(vr0, vi0, vr2, vi2); AP2(vr1, vi1, vr3, vi3); }
            else        { AP2(vr0, vi0, vr1, vi1); AP2(vr2, vi2, vr3, vi3); }
            #undef AP2
        }
        float tr1 = vr2, ti1 = vi2, tr2 = vr3, ti2 = vi3, tr3 = vr1, ti3 = vi1;
        vr1 = tr1; vi1 = ti1; vr2 = tr2; vi2 = ti2; vr3 = tr3; vi3 = ti3;
    }

    const float outv = (vr0 * vr0 + vi0 * vi0 + vr1 * vr1 + vi1 * vi1) -
                       (vr2 * vr2 + vi2 * vi2 + vr3 * vr3 + vi3 * vi3);
    if (k == 0) out[b] = outv;
}

extern "C" void kernel_launch(void* const* d_in, const int* in_sizes, int n_in,
                              void* d_out, int out_size, void* d_ws, size_t ws_size,
                              hipStream_t stream) {
    const float* x_seq = (const float*)d_in[0];
    const float* w_rec = (const float*)d_in[1];
    const float* w_out = (const float*)d_in[2];
    float* out = (float*)d_out;

    const int B = out_size;             // 8192 (T fixed at 32 by the bench)
    const int grid = (B * 16) / 256;    // 512 blocks, 2/CU

    hipLaunchKernelGGL(qrnn_all, dim3(grid), dim3(256), 0, stream,
                       x_seq, w_rec, w_out, out, B);
}